// Round 2
// baseline (70.630 us; speedup 1.0000x reference)
//
#include <hip/hip_runtime.h>

// QuantumProjector: out = post(cumprod(cos(qw)*cos(pre(x))))
// Analytic collapse of the 16-qubit circuit:
//   <Z_j> = prod_{k<=j} cos(q_weights[k]) * cos(angles[b,k])
// Derivation: per-wire RY(w)RX(a)|0> has <Z> = cos(w)cos(a); the CNOT chain
// (control i -> target i+1, sequential) maps bit_j -> XOR of original bits
// 0..j, and the original bits are independent, so the expectation of the
// parity factorizes into the cumulative product.
//
// All tensors are float32 per the reference (NaN forensics in R1 ruled out
// bf16 staging: bf16-decoded inputs can't produce NaN, but f32-misread-as-
// bf16 does).

constexpr int BATCH = 256;
constexpr int DIN   = 1024;
constexpr int NQ    = 16;
constexpr int DOUT  = 1024;

__global__ __launch_bounds__(256, 1) void qp_fused_kernel(
    const float* __restrict__ x,       // [B, DIN]
    const float* __restrict__ W_pre,   // [NQ, DIN]
    const float* __restrict__ b_pre,   // [NQ]
    const float* __restrict__ qw,      // [NQ]
    const float* __restrict__ W_post,  // [DOUT, NQ]
    const float* __restrict__ b_post,  // [DOUT]
    float* __restrict__ out)           // [B, DOUT]
{
    const int b    = blockIdx.x;     // batch row
    const int t    = threadIdx.x;    // 0..255
    const int lane = t & 63;
    const int wave = t >> 6;

    __shared__ float s_partial[4][NQ];  // per-wave partial dot sums
    __shared__ float s_zq[NQ];          // broadcast cumprod

    // ---- pre-net: angles[q] = sum_d x[b,d] * W_pre[q,d] + b_pre[q] ----
    // thread t owns d in {4t .. 4t+3}: 16B float4 loads, fully coalesced.
    const float4 xv = *(const float4*)(x + (size_t)b * DIN + 4 * t);

    float part[NQ];
    #pragma unroll
    for (int q = 0; q < NQ; ++q) {
        const float4 wv = *(const float4*)(W_pre + (size_t)q * DIN + 4 * t);
        part[q] = fmaf(xv.x, wv.x,
                  fmaf(xv.y, wv.y,
                  fmaf(xv.z, wv.z, xv.w * wv.w)));
    }

    // 64-lane butterfly reduce for each of the 16 q's (lane 0 gets the sum)
    #pragma unroll
    for (int off = 32; off > 0; off >>= 1) {
        #pragma unroll
        for (int q = 0; q < NQ; ++q)
            part[q] += __shfl_down(part[q], off, 64);
    }
    if (lane == 0) {
        #pragma unroll
        for (int q = 0; q < NQ; ++q) s_partial[wave][q] = part[q];
    }
    __syncthreads();

    // ---- quantum layer (analytic): cumprod of cos(w_q)*cos(angle_q) ----
    if (t == 0) {
        float prod = 1.f;
        #pragma unroll
        for (int q = 0; q < NQ; ++q) {
            float ang = s_partial[0][q] + s_partial[1][q] +
                        s_partial[2][q] + s_partial[3][q] + b_pre[q];
            prod *= cosf(qw[q]) * cosf(ang);
            s_zq[q] = prod;
        }
    }
    __syncthreads();

    float zq[NQ];
    #pragma unroll
    for (int q = 0; q < NQ; ++q) zq[q] = s_zq[q];  // broadcast (no conflicts)

    // ---- post-net: out[b,o] = sum_q zq[q]*W_post[o,q] + b_post[o] ----
    // thread t owns o in {4t .. 4t+3}; each W_post row is 64B contiguous.
    const int o0 = 4 * t;
    const float4 bp = *(const float4*)(b_post + o0);
    float res[4] = {bp.x, bp.y, bp.z, bp.w};
    #pragma unroll
    for (int j = 0; j < 4; ++j) {
        const float4* wr = (const float4*)(W_post + (size_t)(o0 + j) * NQ);
        float acc = res[j];
        #pragma unroll
        for (int kk = 0; kk < 4; ++kk) {
            const float4 w = wr[kk];
            acc = fmaf(zq[4 * kk + 0], w.x,
                  fmaf(zq[4 * kk + 1], w.y,
                  fmaf(zq[4 * kk + 2], w.z,
                  fmaf(zq[4 * kk + 3], w.w, acc))));
        }
        res[j] = acc;
    }
    *(float4*)(out + (size_t)b * DOUT + o0) =
        make_float4(res[0], res[1], res[2], res[3]);
}

extern "C" void kernel_launch(void* const* d_in, const int* in_sizes, int n_in,
                              void* d_out, int out_size, void* d_ws, size_t ws_size,
                              hipStream_t stream) {
    const float* x      = (const float*)d_in[0];
    const float* W_pre  = (const float*)d_in[1];
    const float* b_pre  = (const float*)d_in[2];
    const float* qw     = (const float*)d_in[3];
    const float* W_post = (const float*)d_in[4];
    const float* b_post = (const float*)d_in[5];
    float* out = (float*)d_out;

    qp_fused_kernel<<<dim3(BATCH), dim3(256), 0, stream>>>(
        x, W_pre, b_pre, qw, W_post, b_post, out);
}

// Round 3
// 67.325 us; speedup vs baseline: 1.0491x; 1.0491x over previous
//
#include <hip/hip_runtime.h>

// QuantumProjector: out = post(cumprod(cos(qw)*cos(pre(x))))
// Analytic collapse of the 16-qubit circuit:
//   <Z_j> = prod_{k<=j} cos(q_weights[k]) * cos(angles[b,k])
// (per-wire <Z> of RY(w)RX(a)|0> is cos(w)cos(a); CNOT chain = prefix-XOR
//  of independent bits, so the parity expectation factorizes.)
//
// R3: single barrier; cos+cumprod computed redundantly by all threads
// (same-address LDS broadcast reads, no serial lane-0 section); __cosf.
// Measured context: timed window is dominated by the harness's 256 MiB
// d_ws re-poison fill (~40 us @ 6.6 TB/s) + input restores; this kernel
// itself is a few us.

constexpr int BATCH = 256;
constexpr int DIN   = 1024;
constexpr int NQ    = 16;
constexpr int DOUT  = 1024;

__global__ __launch_bounds__(256, 1) void qp_fused_kernel(
    const float* __restrict__ x,       // [B, DIN]
    const float* __restrict__ W_pre,   // [NQ, DIN]
    const float* __restrict__ b_pre,   // [NQ]
    const float* __restrict__ qw,      // [NQ]
    const float* __restrict__ W_post,  // [DOUT, NQ]
    const float* __restrict__ b_post,  // [DOUT]
    float* __restrict__ out)           // [B, DOUT]
{
    const int b    = blockIdx.x;     // batch row
    const int t    = threadIdx.x;    // 0..255
    const int lane = t & 63;
    const int wave = t >> 6;

    // [q][wave]: the 4 per-wave partials for one q are 16B contiguous
    // -> each thread re-reads them as one ds_read_b128 broadcast.
    __shared__ float s_partial[NQ][4];

    // ---- pre-net partials: thread t owns d in {4t..4t+3} (float4, coalesced)
    const float4 xv = *(const float4*)(x + (size_t)b * DIN + 4 * t);

    float part[NQ];
    #pragma unroll
    for (int q = 0; q < NQ; ++q) {
        const float4 wv = *(const float4*)(W_pre + (size_t)q * DIN + 4 * t);
        part[q] = fmaf(xv.x, wv.x,
                  fmaf(xv.y, wv.y,
                  fmaf(xv.z, wv.z, xv.w * wv.w)));
    }

    // 64-lane butterfly reduce (lane 0 of each wave holds the wave sum)
    #pragma unroll
    for (int off = 32; off > 0; off >>= 1) {
        #pragma unroll
        for (int q = 0; q < NQ; ++q)
            part[q] += __shfl_down(part[q], off, 64);
    }
    if (lane == 0) {
        #pragma unroll
        for (int q = 0; q < NQ; ++q) s_partial[q][wave] = part[q];
    }
    __syncthreads();   // the ONLY barrier

    // ---- quantum layer (analytic), redundantly on every thread ----
    // LDS reads are same-address across the wave -> broadcast, no conflict.
    float zq[NQ];
    {
        float prod = 1.f;
        #pragma unroll
        for (int q = 0; q < NQ; ++q) {
            const float4 p = *(const float4*)s_partial[q];
            const float ang = (p.x + p.y) + (p.z + p.w) + b_pre[q];
            prod *= __cosf(qw[q]) * __cosf(ang);
            zq[q] = prod;
        }
    }

    // ---- post-net: out[b,o] = sum_q zq[q]*W_post[o,q] + b_post[o] ----
    // thread t owns o in {4t..4t+3}; each W_post row is 64B contiguous.
    const int o0 = 4 * t;
    const float4 bp = *(const float4*)(b_post + o0);
    float res[4] = {bp.x, bp.y, bp.z, bp.w};
    #pragma unroll
    for (int j = 0; j < 4; ++j) {
        const float4* wr = (const float4*)(W_post + (size_t)(o0 + j) * NQ);
        float acc = res[j];
        #pragma unroll
        for (int kk = 0; kk < 4; ++kk) {
            const float4 w = wr[kk];
            acc = fmaf(zq[4 * kk + 0], w.x,
                  fmaf(zq[4 * kk + 1], w.y,
                  fmaf(zq[4 * kk + 2], w.z,
                  fmaf(zq[4 * kk + 3], w.w, acc))));
        }
        res[j] = acc;
    }
    *(float4*)(out + (size_t)b * DOUT + o0) =
        make_float4(res[0], res[1], res[2], res[3]);
}

extern "C" void kernel_launch(void* const* d_in, const int* in_sizes, int n_in,
                              void* d_out, int out_size, void* d_ws, size_t ws_size,
                              hipStream_t stream) {
    const float* x      = (const float*)d_in[0];
    const float* W_pre  = (const float*)d_in[1];
    const float* b_pre  = (const float*)d_in[2];
    const float* qw     = (const float*)d_in[3];
    const float* W_post = (const float*)d_in[4];
    const float* b_post = (const float*)d_in[5];
    float* out = (float*)d_out;

    qp_fused_kernel<<<dim3(BATCH), dim3(256), 0, stream>>>(
        x, W_pre, b_pre, qw, W_post, b_post, out);
}